// Round 1
// baseline (196.908 us; speedup 1.0000x reference)
//
#include <hip/hip_runtime.h>

// MSE_DQ_FK: dual-quaternion denorm -> local rot -> FK -> mse losses -> scalar.
// B=64, T=1024, J=22, C=176. Layout (B,C,T), T contiguous -> thread-per-t
// gives coalesced 256B/wave loads. Only rotation quats (4 of 8 dq channels)
// are read. Telescoping identity: global rot[j] = conj(q0n) * qjn (local[0]
// forced identity + unit-norm cancellation); ik/dec roots are identity.
//
// Round-3 structure:
//  * ROLE SPLIT: each (b,t) handled by two threads of one 512-thread block.
//    role 0: {ik, tgt} streams -> EE losses (joints 4,8,13,17,21)
//    role 1: {dec, ik} streams -> regularizer losses (16 non-sparse joints)
//    2 streams/thread instead of 3 -> 2 waves/SIMD (was 1) hides vmcnt
//    stalls; ik double-read hits L1/L2 (same CU), HBM fetch unchanged.
//  * UNIT-QUAT FROBENIUS IDENTITY: ||R(a)-R(b)||_F^2 = 8*(1 - dot(a,b)^2)
//    for unit quats -> replaces 2x qmat + 27-op diff (~90 VALU) with ~10.
//  * Per-chain register prefetch pipeline retained (prefetch chain k+1
//    while computing chain k; 32-40 outstanding loads per chain).

#define T_DIM 1024

struct Q { float w, x, y, z; };
struct V3 { float x, y, z; };
struct St { Q rot; V3 pos; };

__device__ __forceinline__ Q qmul(const Q a, const Q b) {
    Q r;
    r.w = a.w*b.w - a.x*b.x - a.y*b.y - a.z*b.z;
    r.x = a.w*b.x + a.x*b.w + a.y*b.z - a.z*b.y;
    r.y = a.w*b.y - a.x*b.z + a.y*b.w + a.z*b.x;
    r.z = a.w*b.z + a.x*b.y - a.y*b.x + a.z*b.w;
    return r;
}

__device__ __forceinline__ V3 qrot(const Q q, const V3 v) {
    float tx = 2.f*(q.y*v.z - q.z*v.y);
    float ty = 2.f*(q.z*v.x - q.x*v.z);
    float tz = 2.f*(q.x*v.y - q.y*v.x);
    V3 r;
    r.x = v.x + q.w*tx + (q.y*tz - q.z*ty);
    r.y = v.y + q.w*ty + (q.z*tx - q.x*tz);
    r.z = v.z + q.w*tz + (q.x*ty - q.y*tx);
    return r;
}

// ||R(a)-R(b)||_F^2 for UNIT quaternions:
//   = 6 - 2*tr(R(a)^T R(b)) = 6 - 2*(4*dot(a,b)^2 - 1) = 8*(1 - dot(a,b)^2)
__device__ __forceinline__ float rmdiff2u(const Q a, const Q b) {
    float d = a.w*b.w + a.x*b.x + a.y*b.y + a.z*b.z;
    return 8.f*(1.f - d*d);
}

__device__ __forceinline__ float pdiff2(const V3 a, const V3 b) {
    float dx=a.x-b.x, dy=a.y-b.y, dz=a.z-b.z;
    return dx*dx+dy*dy+dz*dz;
}

__device__ __forceinline__ V3 v3add(const V3 a, const V3 b) {
    return V3{a.x+b.x, a.y+b.y, a.z+b.z};
}

// Denorm raw quat channels (c0..c0+3) then normalize. mean/stdv indexed with
// compile-time-uniform c0 -> scalar loads.
__device__ __forceinline__ Q mkq(const float r[4], const int c0,
                                 const float* __restrict__ mean,
                                 const float* __restrict__ stdv) {
    Q q;
    q.w = r[0]*stdv[c0+0] + mean[c0+0];
    q.x = r[1]*stdv[c0+1] + mean[c0+1];
    q.y = r[2]*stdv[c0+2] + mean[c0+2];
    q.z = r[3]*stdv[c0+3] + mean[c0+3];
    float inv = rsqrtf(q.w*q.w + q.x*q.x + q.y*q.y + q.z*q.z);
    q.w*=inv; q.x*=inv; q.y*=inv; q.z*=inv;
    return q;
}

// Prefetch raw channel dwords for joints J0..J0+N-1 (two streams) into
// register arrays. 8 loads/joint; chains are 4-5 joints -> 32-40 outstanding.
// Both pointers are pre-adjusted so channel base is j*8 uniformly (ik stream
// pointer is shifted by -8*T_DIM to account for its missing root joint).
template<int J0, int N>
__device__ __forceinline__ void pf2(
    const float* __restrict__ xp, const float* __restrict__ yp,
    float (*xr)[4], float (*yr)[4])
{
#pragma unroll
    for (int jj = 0; jj < N; ++jj) {
        const int j = J0 + jj;
#pragma unroll
        for (int c = 0; c < 4; ++c) {
            xr[jj][c] = xp[(j*8 + c)*T_DIM];
            yr[jj][c] = yp[(j*8 + c)*T_DIM];
        }
    }
}

// One joint step for both chains from prefetched raw data.
// PRE: premultiply Y's quat by q0c (tgt stream: non-identity root).
// LOSS: accumulate pos/rot losses at this joint.
template<int J, bool LOSS, bool PRE>
__device__ __forceinline__ void step2(
    St& sx, St& sy,
    const float xr[4], const float yr[4],
    const float* __restrict__ mean, const float* __restrict__ stdv,
    const float* __restrict__ offs, const Q q0c,
    float& ap, float& ar)
{
    const int c0 = J*8;
    Q qx = mkq(xr, c0, mean, stdv);
    Q qy = mkq(yr, c0, mean, stdv);
    if (PRE) qy = qmul(q0c, qy);
    V3 off = { offs[3*J], offs[3*J+1], offs[3*J+2] };
    V3 px = v3add(qrot(sx.rot, off), sx.pos);
    V3 py = v3add(qrot(sy.rot, off), sy.pos);
    if (LOSS) {
        ap += pdiff2(px, py);
        ar += rmdiff2u(qx, qy);
    }
    sx.rot = qx; sx.pos = px;
    sy.rot = qy; sy.pos = py;
}

// Walk all 5 chains for one stream pair with pipelined prefetch.
// EEROLE=true : X=ik, Y=tgt (PRE), losses at EE joints {4,8,13,17,21}
// EEROLE=false: X=dec, Y=ik, losses at the 16 non-sparse joints
template<bool EEROLE>
__device__ __forceinline__ void walk(
    const float* __restrict__ xp, const float* __restrict__ yp,
    const float* __restrict__ mean, const float* __restrict__ stdv,
    const float* __restrict__ offs,
    float& ap, float& ar)
{
    // PARENTS = [0,0,1,2,3, 0,5,6,7, 0,9,10,11,12, 11,14,15,16, 11,18,19,20]
    // Chains: A=1..4(EE4) B=5..8(EE8) C=9..13(EE13,branch@11) D=14..17(EE17)
    //         E=18..21(EE21)
    float Xa[4][4], Ya[4][4];
    float Xb[4][4], Yb[4][4];
    float Xc[5][4], Yc[5][4];
    float Xd[4][4], Yd[4][4];
    float Xe[4][4], Ye[4][4];
    float rq0[4];

    if (EEROLE) {
#pragma unroll
        for (int c = 0; c < 4; ++c) rq0[c] = yp[c*T_DIM];  // tgt root quat
    }
    pf2<1,4>(xp, yp, Xa, Ya);
    pf2<5,4>(xp, yp, Xb, Yb);

    Q q0c = {1.f, 0.f, 0.f, 0.f};
    if (EEROLE) {
        Q q0 = mkq(rq0, 0, mean, stdv);
        q0c = { q0.w, -q0.x, -q0.y, -q0.z };
    }
    const St root = { {1.f,0.f,0.f,0.f}, {0.f,0.f,0.f} };
    St sx, sy;

    // chain A
    sx = root; sy = root;
    step2<1, !EEROLE, EEROLE>(sx,sy, Xa[0],Ya[0], mean,stdv,offs,q0c, ap,ar);
    step2<2, !EEROLE, EEROLE>(sx,sy, Xa[1],Ya[1], mean,stdv,offs,q0c, ap,ar);
    step2<3, !EEROLE, EEROLE>(sx,sy, Xa[2],Ya[2], mean,stdv,offs,q0c, ap,ar);
    step2<4,  EEROLE, EEROLE>(sx,sy, Xa[3],Ya[3], mean,stdv,offs,q0c, ap,ar);

    pf2<9,5>(xp, yp, Xc, Yc);

    // chain B
    sx = root; sy = root;
    step2<5, !EEROLE, EEROLE>(sx,sy, Xb[0],Yb[0], mean,stdv,offs,q0c, ap,ar);
    step2<6, !EEROLE, EEROLE>(sx,sy, Xb[1],Yb[1], mean,stdv,offs,q0c, ap,ar);
    step2<7, !EEROLE, EEROLE>(sx,sy, Xb[2],Yb[2], mean,stdv,offs,q0c, ap,ar);
    step2<8,  EEROLE, EEROLE>(sx,sy, Xb[3],Yb[3], mean,stdv,offs,q0c, ap,ar);

    pf2<14,4>(xp, yp, Xd, Yd);

    // chain C: 9-10-11 (branch point 11), then 12-13
    sx = root; sy = root;
    step2<9,  !EEROLE, EEROLE>(sx,sy, Xc[0],Yc[0], mean,stdv,offs,q0c, ap,ar);
    step2<10, !EEROLE, EEROLE>(sx,sy, Xc[1],Yc[1], mean,stdv,offs,q0c, ap,ar);
    step2<11, !EEROLE, EEROLE>(sx,sy, Xc[2],Yc[2], mean,stdv,offs,q0c, ap,ar);
    const St sx11 = sx, sy11 = sy;
    step2<12, !EEROLE, EEROLE>(sx,sy, Xc[3],Yc[3], mean,stdv,offs,q0c, ap,ar);
    step2<13,  EEROLE, EEROLE>(sx,sy, Xc[4],Yc[4], mean,stdv,offs,q0c, ap,ar);

    pf2<18,4>(xp, yp, Xe, Ye);

    // chain D: 14-17 from branch point
    sx = sx11; sy = sy11;
    step2<14, !EEROLE, EEROLE>(sx,sy, Xd[0],Yd[0], mean,stdv,offs,q0c, ap,ar);
    step2<15, !EEROLE, EEROLE>(sx,sy, Xd[1],Yd[1], mean,stdv,offs,q0c, ap,ar);
    step2<16, !EEROLE, EEROLE>(sx,sy, Xd[2],Yd[2], mean,stdv,offs,q0c, ap,ar);
    step2<17,  EEROLE, EEROLE>(sx,sy, Xd[3],Yd[3], mean,stdv,offs,q0c, ap,ar);

    // chain E: 18-21 from branch point
    sx = sx11; sy = sy11;
    step2<18, !EEROLE, EEROLE>(sx,sy, Xe[0],Ye[0], mean,stdv,offs,q0c, ap,ar);
    step2<19, !EEROLE, EEROLE>(sx,sy, Xe[1],Ye[1], mean,stdv,offs,q0c, ap,ar);
    step2<20, !EEROLE, EEROLE>(sx,sy, Xe[2],Ye[2], mean,stdv,offs,q0c, ap,ar);
    step2<21,  EEROLE, EEROLE>(sx,sy, Xe[3],Ye[3], mean,stdv,offs,q0c, ap,ar);
}

__global__ __launch_bounds__(512, 2) void fk_loss_kernel(
    const float* __restrict__ ik, const float* __restrict__ dec,
    const float* __restrict__ tgt, const float* __restrict__ mean,
    const float* __restrict__ stdv, const float* __restrict__ offs,
    float* __restrict__ out)
{
    __shared__ float swred[8];
    const int tid = threadIdx.x;
    const int role = tid >> 8;       // waves 0-3: EE role, waves 4-7: REG role
    const int lt = tid & 255;
    const int p = blockIdx.x * 256 + lt;
    const int b = p >> 10;           // / T
    const int t = p & 1023;          // % T
    // ik pointer pre-shifted by -8*T_DIM: its array lacks the root joint, so
    // channel base becomes j*8 uniformly (only dereferenced for j >= 1).
    const float* ikp = ik  + (size_t)b * (168*1024) + t - (size_t)(8*T_DIM);
    const float* dep = dec + (size_t)b * (176*1024) + t;
    const float* tgp = tgt + (size_t)b * (176*1024) + t;

    float ap = 0.f, ar = 0.f;
    float loss;
    const float BT = 65536.f;
    if (role == 0) {
        // loss_ee = ee_pos/(B*T*5*3) + ee_rm/(B*T*5*9)
        walk<true>(ikp, tgp, mean, stdv, offs, ap, ar);
        loss = ap * (1.0f/(BT*15.f)) + ar * (1.0f/(BT*45.f));
    } else {
        // loss_reg = 0.1*( reg_pos/(B*T*16*3) + reg_rm/(B*T*16*9) )
        walk<false>(dep, ikp, mean, stdv, offs, ap, ar);
        loss = ap * (0.1f/(BT*48.f)) + ar * (0.1f/(BT*144.f));
    }

    // wave(64) shuffle reduce -> cross-wave via LDS -> one atomic per block
#pragma unroll
    for (int o = 32; o > 0; o >>= 1) loss += __shfl_down(loss, o);
    if ((tid & 63) == 0) swred[tid >> 6] = loss;
    __syncthreads();
    if (tid == 0) {
        float s = 0.f;
#pragma unroll
        for (int i = 0; i < 8; ++i) s += swred[i];
        atomicAdd(out, s);
    }
}

extern "C" void kernel_launch(void* const* d_in, const int* in_sizes, int n_in,
                              void* d_out, int out_size, void* d_ws, size_t ws_size,
                              hipStream_t stream) {
    // inputs (setup_inputs order): input(unused), input_ik, input_decoder,
    // target, mean_dqs, std_dqs, offsets
    const float* ikx  = (const float*)d_in[1];
    const float* dec  = (const float*)d_in[2];
    const float* tgt  = (const float*)d_in[3];
    const float* mean = (const float*)d_in[4];
    const float* stdv = (const float*)d_in[5];
    const float* offs = (const float*)d_in[6];
    float* out = (float*)d_out;

    hipMemsetAsync(out, 0, sizeof(float), stream);
    // 64*1024 poses, 2 role-threads each / 512 threads = 256 blocks
    // (1 block/CU, 8 waves/CU = 2 waves/SIMD)
    fk_loss_kernel<<<256, 512, 0, stream>>>(ikx, dec, tgt, mean, stdv, offs, out);
}